// Round 8
// baseline (125.425 us; speedup 1.0000x reference)
//
#include <hip/hip_runtime.h>
#include <stdint.h>

#define NN 8192      // nodes
#define FF 512       // feature dim
#define HH 64        // hidden
#define CC 10        // classes
#define EE 262144    // edges
#define NTR 512      // train nodes
#define ALPHA_NS 0.2f

#define CAP 96u              // slots per dst row (Poisson(32); P(deg>96) ~ e^-38)
#define EMPTY 0xFFFFFFFFu
#define ROWS_PB 32           // rows per k_init block
#define SLOTS_PB ((NN*CAP)/256u)   // 3072 table slots cleared per k_init block

__device__ __forceinline__ float dot4(float4 a, float4 b){
    return a.x*b.x + a.y*b.y + a.z*b.z + a.w*b.w;
}

// ---------------------------------------------------------------------------
// k_init: per-block independent. Clears table slice + s1, computes v01
// redundantly in LDS, then s_src/s_dst/FW for its 32 rows, local cvec, Db.
// ---------------------------------------------------------------------------
__global__ __launch_bounds__(1024) void k_init(
    const float* __restrict__ W, const float* __restrict__ a,
    const float* __restrict__ h, const float* __restrict__ feat,
    const float* __restrict__ W1, const int* __restrict__ idx_tr,
    const int* __restrict__ labels,
    uint2* __restrict__ tab, float* __restrict__ s1,
    float* __restrict__ s_src, float* __restrict__ s_dst,
    float* __restrict__ FW, float* __restrict__ Db)
{
    __shared__ float v0l[FF];
    __shared__ float v1l[FF];
    __shared__ int chist[CC];
    __shared__ float cvecl[CC];
    __shared__ uint8_t lmark[ROWS_PB];

    const int tid = threadIdx.x;
    const int b   = blockIdx.x;
    const int rbase = b * ROWS_PB;

    // clear this block's slice of the table (3072 uint2 slots)
    for (uint32_t i = tid; i < SLOTS_PB; i += 1024)
        tab[(uint32_t)b*SLOTS_PB + i] = make_uint2(EMPTY, 0u);
    if (tid < ROWS_PB) s1[rbase + tid] = 0.f;

    // v01 in LDS: threads 0..511 -> v0, 512..1023 -> v1
    {
        int f = tid & (FF-1);
        const float* av = (tid < FF) ? a : (a + HH);
        float acc = 0.f;
        for (int hh = 0; hh < HH; ++hh) acc += W[hh*FF + f] * av[hh];
        if (tid < FF) v0l[f] = acc; else v1l[f] = acc;
    }

    if (tid < ROWS_PB) lmark[tid] = 0;
    if (tid < CC) chist[tid] = 0;
    __syncthreads();
    if (tid < NTR){
        int node = idx_tr[tid];
        atomicAdd(&chist[labels[node]], 1);
        unsigned lr = (unsigned)(node - rbase);
        if (lr < (unsigned)ROWS_PB) lmark[lr] = 1;
    }
    __syncthreads();
    if (tid < CC) cvecl[tid] = (float)chist[tid] / (float)NTR;
    __syncthreads();

    // s-dots + FW: 16 waves x 2 rows
    {
        const int wid = tid >> 6, lane = tid & 63;
        const float4* v0 = (const float4*)v0l;
        const float4* v1 = (const float4*)v1l;
        #pragma unroll
        for (int rr = 0; rr < 2; ++rr){
            int row = rbase + wid*2 + rr;
            const float4* hr = (const float4*)(h + (size_t)row*FF);
            float4 x0 = hr[lane*2], x1 = hr[lane*2+1];
            float a0 = dot4(x0, v0[lane*2]) + dot4(x1, v0[lane*2+1]);
            float a1 = dot4(x0, v1[lane*2]) + dot4(x1, v1[lane*2+1]);
            #pragma unroll
            for (int off = 32; off >= 1; off >>= 1){
                a0 += __shfl_xor(a0, off);
                a1 += __shfl_xor(a1, off);
            }
            if (lane == 0){ s_src[row] = a0; s_dst[row] = a1; }

            const float4* fr = (const float4*)(feat + (size_t)row*FF);
            float4 f0 = fr[lane*2], f1 = fr[lane*2+1];
            float acc[CC];
            #pragma unroll
            for (int c = 0; c < CC; ++c){
                const float4* wr = (const float4*)(W1 + c*FF);
                acc[c] = dot4(f0, wr[lane*2]) + dot4(f1, wr[lane*2+1]);
            }
            #pragma unroll
            for (int c = 0; c < CC; ++c){
                float r = acc[c];
                #pragma unroll
                for (int off = 32; off >= 1; off >>= 1) r += __shfl_xor(r, off);
                acc[c] = r;
            }
            if (lane == 0){
                #pragma unroll
                for (int c = 0; c < CC; ++c) FW[row*CC + c] = acc[c];
            }
        }
    }

    // Db for this block's 32 rows (320 elements); u1 == Db (spmv step 2 reads it)
    if (tid < ROWS_PB*CC){
        int il = tid / CC, c = tid - il*CC;
        int row = rbase + il;
        float v = 0.f;
        if (lmark[il]) v = ((labels[row] == c) ? 1.0f : 0.0f) - cvecl[c];
        Db[row*CC + c] = v;
    }
}

// ---------------------------------------------------------------------------
// k_build: one thread per edge. Dedup + placement in one step: open-addressing
// within the dst row's 96 slots, keyed by src (same src -> same probe sequence
// -> exactly one owner). Load-before-CAS skips RMW on occupied slots. Owner
// stores raw e adjacent to the key (same line) and accumulates s1[src].
// ---------------------------------------------------------------------------
__global__ void k_build(const int* __restrict__ ei, const float* __restrict__ s_src,
                        const float* __restrict__ s_dst,
                        uint2* __restrict__ tab, float* __restrict__ s1)
{
    int k = blockIdx.x*256 + threadIdx.x;
    int src = ei[k], dst = ei[EE + k];
    uint32_t base = (uint32_t)dst * CAP;
    uint32_t p = (uint32_t)(((uint64_t)((uint32_t)src * 2654435761u) * CAP) >> 32);
    float z = s_src[src] + s_dst[dst];
    z = (z >= 0.f) ? z : ALPHA_NS * z;
    float e = expf(z);
    for (uint32_t it = 0; it < CAP; ++it){
        uint32_t cur = tab[base + p].x;
        if (cur == (uint32_t)src) break;            // duplicate pair -> drop
        if (cur == EMPTY){
            uint32_t prev = atomicCAS(&tab[base + p].x, EMPTY, (uint32_t)src);
            if (prev == EMPTY){
                tab[base + p].y = __float_as_uint(e);
                atomicAdd(&s1[src], e);
                break;
            }
            if (prev == (uint32_t)src) break;       // lost to our duplicate
            // lost to another src: keep probing
        }
        p = (p + 1u == CAP) ? 0u : p + 1u;
    }
}

// ---------------------------------------------------------------------------
// k_fixup: one wave per row. Ballot-compact the row's slots in place while
// baking w = e / s1[src]; insert self-loop (w=1) for zero-out-degree rows;
// write cnt. Rows with s1==0 never appear as src, so no cross-row race.
// ---------------------------------------------------------------------------
__global__ __launch_bounds__(1024) void k_fixup(
    uint2* __restrict__ tab, const float* __restrict__ s1,
    uint32_t* __restrict__ cnt)
{
    const int tid = threadIdx.x;
    const int wid = tid >> 6, lane = tid & 63;
    const int row = blockIdx.x*16 + wid;     // 512 blocks x 16 waves
    const uint32_t base = (uint32_t)row * CAP;

    uint2 v0 = tab[base + lane];
    uint2 v1 = (lane < (int)(CAP - 64u)) ? tab[base + 64 + lane] : make_uint2(EMPTY, 0u);

    uint64_t m0 = __ballot(v0.x != EMPTY);
    uint64_t m1 = __ballot((lane < (int)(CAP - 64u)) && v1.x != EMPTY);
    uint64_t below = (1ull << lane) - 1ull;
    uint32_t t0   = (uint32_t)__popcll(m0);
    uint32_t pos0 = (uint32_t)__popcll(m0 & below);
    uint32_t pos1 = t0 + (uint32_t)__popcll(m1 & below);
    uint32_t total = t0 + (uint32_t)__popcll(m1);

    if (v0.x != EMPTY){
        float w = __uint_as_float(v0.y) / s1[v0.x];
        tab[base + pos0] = make_uint2(v0.x, __float_as_uint(w));
    }
    if (lane < (int)(CAP - 64u) && v1.x != EMPTY){
        float w = __uint_as_float(v1.y) / s1[v1.x];
        tab[base + pos1] = make_uint2(v1.x, __float_as_uint(w));
    }

    if (lane == 0){
        if (s1[row] == 0.f){                 // zero out-degree -> self loop, w=1
            tab[base + total] = make_uint2((uint32_t)row, __float_as_uint(1.0f));
            total += 1u;
        }
        cnt[row] = total;
    }
}

// ---------------------------------------------------------------------------
// k_spmv: 2 rows per wave (32-lane halves). Weights pre-normalized:
// u_out[i] = sum_p w[p] * u_in[src[p]] + Db[i] (+FW at t=7).
// ---------------------------------------------------------------------------
__global__ __launch_bounds__(1024) void k_spmv(
    const uint32_t* __restrict__ cnt, const uint2* __restrict__ tab,
    const float* __restrict__ uh_in, const float* __restrict__ Db,
    const float* __restrict__ FW, float* __restrict__ uout, int add_fw)
{
    const int tid = threadIdx.x;
    const int wid = tid >> 6, lane = tid & 63;
    const int sub = lane >> 5, l32 = lane & 31;
    const int row = (blockIdx.x*16 + wid)*2 + sub;   // 256 blocks
    const uint2* tp = tab + (uint32_t)row * CAP;
    const uint32_t n = cnt[row];

    float acc[CC];
    #pragma unroll
    for (int c = 0; c < CC; ++c) acc[c] = 0.f;
    for (uint32_t p = (uint32_t)l32; p < n; p += 32u){
        uint2 v = tp[p];
        float w = __uint_as_float(v.y);
        const float2* u2 = (const float2*)(uh_in + (size_t)v.x*CC);
        #pragma unroll
        for (int q = 0; q < 5; ++q){
            float2 u = u2[q];
            acc[2*q]   += w * u.x;
            acc[2*q+1] += w * u.y;
        }
    }
    #pragma unroll
    for (int c = 0; c < CC; ++c){
        float r = acc[c];
        #pragma unroll
        for (int off = 16; off >= 1; off >>= 1) r += __shfl_xor(r, off);
        acc[c] = r;
    }
    if (l32 == 0){
        const float* db = Db + row*CC;
        float* o = uout + row*CC;
        if (add_fw){
            const float* fw = FW + row*CC;
            #pragma unroll
            for (int c = 0; c < CC; ++c) o[c] = acc[c] + db[c] + fw[c];
        } else {
            #pragma unroll
            for (int c = 0; c < CC; ++c) o[c] = acc[c] + db[c];
        }
    }
}

extern "C" void kernel_launch(void* const* d_in, const int* in_sizes, int n_in,
                              void* d_out, int out_size, void* d_ws, size_t ws_size,
                              hipStream_t stream){
    const float* h    = (const float*)d_in[0];
    const float* W    = (const float*)d_in[1];
    const float* a    = (const float*)d_in[2];
    const float* W1   = (const float*)d_in[3];
    const float* feat = (const float*)d_in[4];
    const int* ei     = (const int*)d_in[5];
    const int* idx_tr = (const int*)d_in[6];
    const int* labels = (const int*)d_in[7];
    float* out = (float*)d_out;

    char* wsp = (char*)d_ws;
    auto alloc = [&](size_t bytes)->void*{
        void* p = (void*)wsp;
        wsp += (bytes + 255) & ~(size_t)255;
        return p;
    };
    uint2*    tab   = (uint2*)   alloc((size_t)NN*CAP*8);   // 6 MB
    float*    s1    = (float*)   alloc(NN*4);
    uint32_t* cnt   = (uint32_t*)alloc(NN*4);
    float*    s_src = (float*)   alloc(NN*4);
    float*    s_dst = (float*)   alloc(NN*4);
    float*    FW    = (float*)   alloc((size_t)NN*CC*4);
    float*    Db    = (float*)   alloc((size_t)NN*CC*4);
    float*    uA    = (float*)   alloc((size_t)NN*CC*4);
    float*    uB    = (float*)   alloc((size_t)NN*CC*4);

    k_init <<<256, 1024, 0, stream>>>(W, a, h, feat, W1, idx_tr, labels,
                                      tab, s1, s_src, s_dst, FW, Db);
    k_build<<<EE/256, 256, 0, stream>>>(ei, s_src, s_dst, tab, s1);
    k_fixup<<<NN/16, 1024, 0, stream>>>(tab, s1, cnt);

    // u1 == Db; diffusion steps t=2..10 (FW added at t=7, t=10 writes out)
    const float* cur = Db;
    float* nxt = uB;
    float* alt = uA;
    for (int t = 2; t <= 10; ++t){
        float* dst = (t == 10) ? out : nxt;
        k_spmv<<<NN/32, 1024, 0, stream>>>(cnt, tab, cur, Db, FW, dst,
                                           (t == 7) ? 1 : 0);
        cur = dst;
        nxt = alt;
        alt = dst == out ? alt : dst;
        // simple two-buffer rotation: after first step, alternate uA/uB
        if (t == 2){ nxt = uA; alt = uB; }
        else { float* tmp; tmp = (cur == uA) ? uB : uA; nxt = tmp; alt = (float*)cur; }
    }
}

// Round 9
// 102.985 us; speedup vs baseline: 1.2179x; 1.2179x over previous
//
#include <hip/hip_runtime.h>
#include <stdint.h>

#define NN 8192      // nodes
#define FF 512       // feature dim
#define HH 64        // hidden
#define CC 10        // classes
#define PAD 12       // padded channel stride (3x float4)
#define EE 262144    // edges
#define NTR 512      // train nodes
#define ALPHA_NS 0.2f

#define CAP 96u              // slots per dst row (Poisson(32); P(deg>96) ~ e^-38)
#define EMPTY 0xFFFFFFFFu
#define ROWS_PB 32           // rows per k_init block
#define SLOTS_PB ((NN*CAP)/256u)   // 3072 csrc2 slots cleared per k_init block

__device__ __forceinline__ float dot4(float4 a, float4 b){
    return a.x*b.x + a.y*b.y + a.z*b.z + a.w*b.w;
}

// ---------------------------------------------------------------------------
// k_init: per-block independent. Clears csrc2 slice + s1, computes v01
// redundantly in LDS, then s_src/s_dst/FW for its 32 rows, local cvec,
// padded Db (pads zeroed: Db doubles as u1, read via float4).
// ---------------------------------------------------------------------------
__global__ __launch_bounds__(1024) void k_init(
    const float* __restrict__ W, const float* __restrict__ a,
    const float* __restrict__ h, const float* __restrict__ feat,
    const float* __restrict__ W1, const int* __restrict__ idx_tr,
    const int* __restrict__ labels,
    uint32_t* __restrict__ csrc2, float* __restrict__ s1,
    float* __restrict__ s_src, float* __restrict__ s_dst,
    float* __restrict__ FW, float* __restrict__ Db)
{
    __shared__ float v0l[FF];
    __shared__ float v1l[FF];
    __shared__ int chist[CC];
    __shared__ float cvecl[CC];
    __shared__ uint8_t lmark[ROWS_PB];

    const int tid = threadIdx.x;
    const int b   = blockIdx.x;
    const int rbase = b * ROWS_PB;

    for (uint32_t i = tid; i < SLOTS_PB; i += 1024)
        csrc2[(uint32_t)b*SLOTS_PB + i] = EMPTY;
    if (tid < ROWS_PB) s1[rbase + tid] = 0.f;

    // v01 in LDS: threads 0..511 -> v0, 512..1023 -> v1
    {
        int f = tid & (FF-1);
        const float* av = (tid < FF) ? a : (a + HH);
        float acc = 0.f;
        for (int hh = 0; hh < HH; ++hh) acc += W[hh*FF + f] * av[hh];
        if (tid < FF) v0l[f] = acc; else v1l[f] = acc;
    }

    if (tid < ROWS_PB) lmark[tid] = 0;
    if (tid < CC) chist[tid] = 0;
    __syncthreads();
    if (tid < NTR){
        int node = idx_tr[tid];
        atomicAdd(&chist[labels[node]], 1);
        unsigned lr = (unsigned)(node - rbase);
        if (lr < (unsigned)ROWS_PB) lmark[lr] = 1;
    }
    __syncthreads();
    if (tid < CC) cvecl[tid] = (float)chist[tid] / (float)NTR;
    __syncthreads();

    // s-dots + FW: 16 waves x 2 rows
    {
        const int wid = tid >> 6, lane = tid & 63;
        const float4* v0 = (const float4*)v0l;
        const float4* v1 = (const float4*)v1l;
        #pragma unroll
        for (int rr = 0; rr < 2; ++rr){
            int row = rbase + wid*2 + rr;
            const float4* hr = (const float4*)(h + (size_t)row*FF);
            float4 x0 = hr[lane*2], x1 = hr[lane*2+1];
            float a0 = dot4(x0, v0[lane*2]) + dot4(x1, v0[lane*2+1]);
            float a1 = dot4(x0, v1[lane*2]) + dot4(x1, v1[lane*2+1]);
            #pragma unroll
            for (int off = 32; off >= 1; off >>= 1){
                a0 += __shfl_xor(a0, off);
                a1 += __shfl_xor(a1, off);
            }
            if (lane == 0){ s_src[row] = a0; s_dst[row] = a1; }

            const float4* fr = (const float4*)(feat + (size_t)row*FF);
            float4 f0 = fr[lane*2], f1 = fr[lane*2+1];
            float acc[CC];
            #pragma unroll
            for (int c = 0; c < CC; ++c){
                const float4* wr = (const float4*)(W1 + c*FF);
                acc[c] = dot4(f0, wr[lane*2]) + dot4(f1, wr[lane*2+1]);
            }
            #pragma unroll
            for (int c = 0; c < CC; ++c){
                float r = acc[c];
                #pragma unroll
                for (int off = 32; off >= 1; off >>= 1) r += __shfl_xor(r, off);
                acc[c] = r;
            }
            if (lane == 0){
                #pragma unroll
                for (int c = 0; c < CC; ++c) FW[row*PAD + c] = acc[c];
            }
        }
    }

    // padded Db (u1) for this block's 32 rows: 32*12 = 384 elements
    if (tid < ROWS_PB*PAD){
        int il = tid / PAD, c = tid - il*PAD;
        int row = rbase + il;
        float v = 0.f;
        if (c < CC && lmark[il]) v = ((labels[row] == c) ? 1.0f : 0.0f) - cvecl[c];
        Db[row*PAD + c] = v;
    }
}

// ---------------------------------------------------------------------------
// k_build (round-7 layout): one thread per edge, CAS-direct on dense u32 keys
// (16 slots/line), value store to separate e2, s1 via global atomicAdd.
// ---------------------------------------------------------------------------
__global__ void k_build(const int* __restrict__ ei, const float* __restrict__ s_src,
                        const float* __restrict__ s_dst,
                        uint32_t* __restrict__ csrc2, float* __restrict__ e2,
                        float* __restrict__ s1)
{
    int k = blockIdx.x*256 + threadIdx.x;
    int src = ei[k], dst = ei[EE + k];
    uint32_t base = (uint32_t)dst * CAP;
    uint32_t p = (uint32_t)(((uint64_t)((uint32_t)src * 2654435761u) * CAP) >> 32);
    float z = s_src[src] + s_dst[dst];
    z = (z >= 0.f) ? z : ALPHA_NS * z;
    float e = expf(z);
    for (uint32_t it = 0; it < CAP; ++it){
        uint32_t prev = atomicCAS(&csrc2[base + p], EMPTY, (uint32_t)src);
        if (prev == EMPTY){
            e2[base + p] = e;
            atomicAdd(&s1[src], e);
            break;
        }
        if (prev == (uint32_t)src) break;   // duplicate pair (same value) -> drop
        p = (p + 1u == CAP) ? 0u : p + 1u;
    }
}

// ---------------------------------------------------------------------------
// k_fixup: one wave per row. Ballot-compact into interleaved tabc while baking
// w = e / s1[src]; self-loop (w=1) for zero-out-degree rows; write cnt.
// ---------------------------------------------------------------------------
__global__ __launch_bounds__(1024) void k_fixup(
    const uint32_t* __restrict__ csrc2, const float* __restrict__ e2,
    const float* __restrict__ s1, uint2* __restrict__ tabc,
    uint32_t* __restrict__ cnt)
{
    const int tid = threadIdx.x;
    const int wid = tid >> 6, lane = tid & 63;
    const int row = blockIdx.x*16 + wid;     // 512 blocks x 16 waves
    const uint32_t base = (uint32_t)row * CAP;

    uint32_t c0 = csrc2[base + lane];
    uint32_t c1 = (lane < (int)(CAP - 64u)) ? csrc2[base + 64 + lane] : EMPTY;
    float    e0 = e2[base + lane];
    float    e1 = (lane < (int)(CAP - 64u)) ? e2[base + 64 + lane] : 0.f;

    uint64_t m0 = __ballot(c0 != EMPTY);
    uint64_t m1 = __ballot((lane < (int)(CAP - 64u)) && c1 != EMPTY);
    uint64_t below = (1ull << lane) - 1ull;
    uint32_t t0   = (uint32_t)__popcll(m0);
    uint32_t pos0 = (uint32_t)__popcll(m0 & below);
    uint32_t pos1 = t0 + (uint32_t)__popcll(m1 & below);
    uint32_t total = t0 + (uint32_t)__popcll(m1);

    if (c0 != EMPTY){
        float w = e0 / s1[c0];
        tabc[base + pos0] = make_uint2(c0, __float_as_uint(w));
    }
    if (lane < (int)(CAP - 64u) && c1 != EMPTY){
        float w = e1 / s1[c1];
        tabc[base + pos1] = make_uint2(c1, __float_as_uint(w));
    }

    if (lane == 0){
        if (s1[row] == 0.f){                 // zero out-degree -> self loop, w=1
            tabc[base + total] = make_uint2((uint32_t)row, __float_as_uint(1.0f));
            total += 1u;
        }
        cnt[row] = total;
    }
}

// ---------------------------------------------------------------------------
// k_spmv: 16-lane row groups (4 rows/wave), 3x float4 gathers on 12-padded u.
// u_out[i] = sum_p w[p]*u_in[src[p]] + Db[i] (+FW at t=7); t=10 -> dense out.
// ---------------------------------------------------------------------------
__global__ __launch_bounds__(256) void k_spmv(
    const uint32_t* __restrict__ cnt, const uint2* __restrict__ tabc,
    const float* __restrict__ uh_in, const float* __restrict__ Db,
    const float* __restrict__ FW, float* __restrict__ uout,
    int add_fw, int final_step)
{
    const int tid = threadIdx.x;
    const int wid = tid >> 6, lane = tid & 63;
    const int l16 = lane & 15;
    const int row = blockIdx.x*16 + wid*4 + (lane >> 4);   // 512 blocks
    const uint2* tp = tabc + (uint32_t)row * CAP;
    const uint32_t n = cnt[row];

    float acc[PAD];
    #pragma unroll
    for (int c = 0; c < PAD; ++c) acc[c] = 0.f;
    for (uint32_t p = (uint32_t)l16; p < n; p += 16u){
        uint2 v = tp[p];
        float w = __uint_as_float(v.y);
        const float4* u4 = (const float4*)(uh_in + (size_t)v.x*PAD);
        float4 u0 = u4[0], u1 = u4[1], u2 = u4[2];
        acc[0] += w*u0.x; acc[1] += w*u0.y; acc[2]  += w*u0.z; acc[3]  += w*u0.w;
        acc[4] += w*u1.x; acc[5] += w*u1.y; acc[6]  += w*u1.z; acc[7]  += w*u1.w;
        acc[8] += w*u2.x; acc[9] += w*u2.y; acc[10] += w*u2.z; acc[11] += w*u2.w;
    }
    #pragma unroll
    for (int c = 0; c < PAD; ++c){
        float r = acc[c];
        #pragma unroll
        for (int off = 8; off >= 1; off >>= 1) r += __shfl_xor(r, off, 16);
        acc[c] = r;
    }
    // parallel epilogue: lane l16 handles channel l16
    float v = acc[0];
    #pragma unroll
    for (int c = 1; c < PAD; ++c) v = (l16 == c) ? acc[c] : v;
    if (l16 < CC){
        v += Db[row*PAD + l16];
        if (add_fw) v += FW[row*PAD + l16];
    } else {
        v = 0.f;
    }
    if (final_step){
        if (l16 < CC) uout[(size_t)row*CC + l16] = v;
    } else {
        if (l16 < PAD) uout[(size_t)row*PAD + l16] = v;
    }
}

extern "C" void kernel_launch(void* const* d_in, const int* in_sizes, int n_in,
                              void* d_out, int out_size, void* d_ws, size_t ws_size,
                              hipStream_t stream){
    const float* h    = (const float*)d_in[0];
    const float* W    = (const float*)d_in[1];
    const float* a    = (const float*)d_in[2];
    const float* W1   = (const float*)d_in[3];
    const float* feat = (const float*)d_in[4];
    const int* ei     = (const int*)d_in[5];
    const int* idx_tr = (const int*)d_in[6];
    const int* labels = (const int*)d_in[7];
    float* out = (float*)d_out;

    char* wsp = (char*)d_ws;
    auto alloc = [&](size_t bytes)->void*{
        void* p = (void*)wsp;
        wsp += (bytes + 255) & ~(size_t)255;
        return p;
    };
    uint32_t* csrc2 = (uint32_t*)alloc((size_t)NN*CAP*4);   // 3 MB
    float*    e2    = (float*)   alloc((size_t)NN*CAP*4);   // 3 MB
    uint2*    tabc  = (uint2*)   alloc((size_t)NN*CAP*8);   // 6 MB
    float*    s1    = (float*)   alloc(NN*4);
    uint32_t* cnt   = (uint32_t*)alloc(NN*4);
    float*    s_src = (float*)   alloc(NN*4);
    float*    s_dst = (float*)   alloc(NN*4);
    float*    FW    = (float*)   alloc((size_t)NN*PAD*4);
    float*    Db    = (float*)   alloc((size_t)NN*PAD*4);
    float*    uA    = (float*)   alloc((size_t)NN*PAD*4);
    float*    uB    = (float*)   alloc((size_t)NN*PAD*4);

    k_init <<<256, 1024, 0, stream>>>(W, a, h, feat, W1, idx_tr, labels,
                                      csrc2, s1, s_src, s_dst, FW, Db);
    k_build<<<EE/256, 256, 0, stream>>>(ei, s_src, s_dst, csrc2, e2, s1);
    k_fixup<<<NN/16, 1024, 0, stream>>>(csrc2, e2, s1, tabc, cnt);

    // u1 == Db; steps t=2..10: even t -> uA, odd t -> uB, t=10 -> out
    const float* cur = Db;
    for (int t = 2; t <= 10; ++t){
        float* dst = (t == 10) ? out : ((t & 1) ? uB : uA);
        k_spmv<<<NN/16, 256, 0, stream>>>(cnt, tabc, cur, Db, FW, dst,
                                          (t == 7) ? 1 : 0, (t == 10) ? 1 : 0);
        cur = dst;
    }
}

// Round 10
// 99.398 us; speedup vs baseline: 1.2618x; 1.0361x over previous
//
#include <hip/hip_runtime.h>
#include <stdint.h>

#define NN 8192      // nodes
#define FF 512       // feature dim
#define HH 64        // hidden
#define CC 10        // classes
#define PAD 12       // padded channel stride (3x float4)
#define EE 262144    // edges
#define NTR 512      // train nodes
#define ALPHA_NS 0.2f

#define CAP 96u              // slots per dst row (Poisson(32); P(deg>96) ~ e^-38)
#define EMPTY 0xFFFFFFFFu
#define ROWS_PB 32           // rows per k_init block
#define SLOTS_PB ((NN*CAP)/256u)   // 3072 csrc2 slots cleared per k_init block
#define FB 128               // fixup blocks

__device__ __forceinline__ float dot4(float4 a, float4 b){
    return a.x*b.x + a.y*b.y + a.z*b.z + a.w*b.w;
}

// ---------------------------------------------------------------------------
// k_init: per-block independent. Clears csrc2 slice, computes v01 redundantly
// in LDS, s_src/s_dst/FW for its 32 rows, local cvec, padded Db (pads zero).
// ---------------------------------------------------------------------------
__global__ __launch_bounds__(1024) void k_init(
    const float* __restrict__ W, const float* __restrict__ a,
    const float* __restrict__ h, const float* __restrict__ feat,
    const float* __restrict__ W1, const int* __restrict__ idx_tr,
    const int* __restrict__ labels,
    uint32_t* __restrict__ csrc2,
    float* __restrict__ s_src, float* __restrict__ s_dst,
    float* __restrict__ FW, float* __restrict__ Db)
{
    __shared__ float v0l[FF];
    __shared__ float v1l[FF];
    __shared__ int chist[CC];
    __shared__ float cvecl[CC];
    __shared__ uint8_t lmark[ROWS_PB];

    const int tid = threadIdx.x;
    const int b   = blockIdx.x;
    const int rbase = b * ROWS_PB;

    for (uint32_t i = tid; i < SLOTS_PB; i += 1024)
        csrc2[(uint32_t)b*SLOTS_PB + i] = EMPTY;

    // v01 in LDS: threads 0..511 -> v0, 512..1023 -> v1
    {
        int f = tid & (FF-1);
        const float* av = (tid < FF) ? a : (a + HH);
        float acc = 0.f;
        for (int hh = 0; hh < HH; ++hh) acc += W[hh*FF + f] * av[hh];
        if (tid < FF) v0l[f] = acc; else v1l[f] = acc;
    }

    if (tid < ROWS_PB) lmark[tid] = 0;
    if (tid < CC) chist[tid] = 0;
    __syncthreads();
    if (tid < NTR){
        int node = idx_tr[tid];
        atomicAdd(&chist[labels[node]], 1);
        unsigned lr = (unsigned)(node - rbase);
        if (lr < (unsigned)ROWS_PB) lmark[lr] = 1;
    }
    __syncthreads();
    if (tid < CC) cvecl[tid] = (float)chist[tid] / (float)NTR;
    __syncthreads();

    // s-dots + FW: 16 waves x 2 rows
    {
        const int wid = tid >> 6, lane = tid & 63;
        const float4* v0 = (const float4*)v0l;
        const float4* v1 = (const float4*)v1l;
        #pragma unroll
        for (int rr = 0; rr < 2; ++rr){
            int row = rbase + wid*2 + rr;
            const float4* hr = (const float4*)(h + (size_t)row*FF);
            float4 x0 = hr[lane*2], x1 = hr[lane*2+1];
            float a0 = dot4(x0, v0[lane*2]) + dot4(x1, v0[lane*2+1]);
            float a1 = dot4(x0, v1[lane*2]) + dot4(x1, v1[lane*2+1]);
            #pragma unroll
            for (int off = 32; off >= 1; off >>= 1){
                a0 += __shfl_xor(a0, off);
                a1 += __shfl_xor(a1, off);
            }
            if (lane == 0){ s_src[row] = a0; s_dst[row] = a1; }

            const float4* fr = (const float4*)(feat + (size_t)row*FF);
            float4 f0 = fr[lane*2], f1 = fr[lane*2+1];
            float acc[CC];
            #pragma unroll
            for (int c = 0; c < CC; ++c){
                const float4* wr = (const float4*)(W1 + c*FF);
                acc[c] = dot4(f0, wr[lane*2]) + dot4(f1, wr[lane*2+1]);
            }
            #pragma unroll
            for (int c = 0; c < CC; ++c){
                float r = acc[c];
                #pragma unroll
                for (int off = 32; off >= 1; off >>= 1) r += __shfl_xor(r, off);
                acc[c] = r;
            }
            if (lane == 0){
                #pragma unroll
                for (int c = 0; c < CC; ++c) FW[row*PAD + c] = acc[c];
            }
        }
    }

    // padded Db for this block's 32 rows: 32*12 = 384 elements
    if (tid < ROWS_PB*PAD){
        int il = tid / PAD, c = tid - il*PAD;
        int row = rbase + il;
        float v = 0.f;
        if (c < CC && lmark[il]) v = ((labels[row] == c) ? 1.0f : 0.0f) - cvecl[c];
        Db[row*PAD + c] = v;
    }
}

// ---------------------------------------------------------------------------
// k_build: pure CAS dedup+placement, one thread per edge. No value stores,
// no atomicAdds, no s-dot loads. Key = src in the dst row's 96 slots.
// ---------------------------------------------------------------------------
__global__ void k_build(const int* __restrict__ ei, uint32_t* __restrict__ csrc2)
{
    int k = blockIdx.x*256 + threadIdx.x;
    uint32_t src = (uint32_t)ei[k];
    uint32_t dst = (uint32_t)ei[EE + k];
    uint32_t base = dst * CAP;
    uint32_t p = (uint32_t)(((uint64_t)(src * 2654435761u) * CAP) >> 32);
    for (uint32_t it = 0; it < CAP; ++it){
        uint32_t prev = atomicCAS(&csrc2[base + p], EMPTY, src);
        if (prev == EMPTY || prev == src) break;   // placed, or duplicate -> drop
        p = (p + 1u == CAP) ? 0u : p + 1u;
    }
}

// ---------------------------------------------------------------------------
// k_fixup: 128 blocks x 1024 threads; 16-lane group per row (4 rows/wave).
// Compacts row slots into tabc while recomputing e = exp(leaky(s_src+s_dst)),
// accumulates s1 partials in LDS (no global atomics), writes cnt.
// ---------------------------------------------------------------------------
__global__ __launch_bounds__(1024) void k_fixup(
    const uint32_t* __restrict__ csrc2, const float* __restrict__ s_src,
    const float* __restrict__ s_dst, uint2* __restrict__ tabc,
    uint32_t* __restrict__ cnt, float* __restrict__ s1p)
{
    __shared__ float s1l[NN];    // 32 KB
    const int tid = threadIdx.x;
    const int b   = blockIdx.x;
    const int wid = tid >> 6, lane = tid & 63;
    const int g   = lane >> 4, l16 = lane & 15;
    const int row = (b*16 + wid)*4 + g;      // 128 blocks x 16 waves x 4 rows
    const uint32_t base = (uint32_t)row * CAP;

    for (int i = tid; i < NN; i += 1024) s1l[i] = 0.f;
    __syncthreads();

    const float sdst = s_dst[row];
    uint32_t running = 0;
    #pragma unroll
    for (int step = 0; step < 6; ++step){     // 6*16 = 96 = CAP
        uint32_t key = csrc2[base + step*16 + l16];
        bool valid = (key != EMPTY);
        uint64_t bal = __ballot(valid);
        uint32_t grp = (uint32_t)((bal >> (g*16)) & 0xFFFFull);
        uint32_t rank = (uint32_t)__popc(grp & ((1u << l16) - 1u));
        if (valid){
            float z = s_src[key] + sdst;
            z = (z >= 0.f) ? z : ALPHA_NS * z;
            float e = expf(z);
            tabc[base + running + rank] = make_uint2(key, __float_as_uint(e));
            atomicAdd(&s1l[key], e);          // LDS atomic
        }
        running += (uint32_t)__popc(grp);
    }
    if (l16 == 0) cnt[row] = running;
    __syncthreads();
    for (int i = tid; i < NN; i += 1024) s1p[(size_t)b*NN + i] = s1l[i];
}

// ---------------------------------------------------------------------------
// k_s1red: thread per row. Reduce s1 partials; self-loop append for s1==0
// rows (row-local: bump cnt, add {row,1} entry); write inv_s1 and u-hat-1 =
// Db / s1 (padded).
// ---------------------------------------------------------------------------
__global__ __launch_bounds__(256) void k_s1red(
    const float* __restrict__ s1p, uint2* __restrict__ tabc,
    uint32_t* __restrict__ cnt, const float* __restrict__ Db,
    float* __restrict__ invs1, float* __restrict__ uh1)
{
    int row = blockIdx.x*256 + threadIdx.x;
    float s = 0.f;
    for (int b = 0; b < FB; ++b) s += s1p[(size_t)b*NN + row];
    if (s == 0.f){                       // zero out-degree -> self loop, e=1
        uint32_t c = cnt[row];
        tabc[(uint32_t)row*CAP + c] = make_uint2((uint32_t)row, __float_as_uint(1.0f));
        cnt[row] = c + 1u;
        s = 1.0f;
    }
    float inv = 1.0f / s;
    invs1[row] = inv;
    const float4* d4 = (const float4*)(Db + (size_t)row*PAD);
    float4* u4 = (float4*)(uh1 + (size_t)row*PAD);
    #pragma unroll
    for (int q = 0; q < 3; ++q){
        float4 v = d4[q];
        v.x *= inv; v.y *= inv; v.z *= inv; v.w *= inv;
        u4[q] = v;
    }
}

// ---------------------------------------------------------------------------
// k_spmv: 16-lane row groups (4 rows/wave), 3x float4 gathers on 12-padded
// u-hat. acc = sum e * uh_in[src]; u = acc + Db (+FW at t=7);
// non-final: store uh_out = u * inv_s1 (padded); final: store u dense.
// ---------------------------------------------------------------------------
__global__ __launch_bounds__(256) void k_spmv(
    const uint32_t* __restrict__ cnt, const uint2* __restrict__ tabc,
    const float* __restrict__ uh_in, const float* __restrict__ Db,
    const float* __restrict__ FW, const float* __restrict__ invs1,
    float* __restrict__ uout, int add_fw, int final_step)
{
    const int tid = threadIdx.x;
    const int wid = tid >> 6, lane = tid & 63;
    const int l16 = lane & 15;
    const int row = blockIdx.x*16 + wid*4 + (lane >> 4);   // 512 blocks
    const uint2* tp = tabc + (uint32_t)row * CAP;
    const uint32_t n = cnt[row];

    float acc[PAD];
    #pragma unroll
    for (int c = 0; c < PAD; ++c) acc[c] = 0.f;
    for (uint32_t p = (uint32_t)l16; p < n; p += 16u){
        uint2 v = tp[p];
        float w = __uint_as_float(v.y);
        const float4* u4 = (const float4*)(uh_in + (size_t)v.x*PAD);
        float4 u0 = u4[0], u1 = u4[1], u2 = u4[2];
        acc[0] += w*u0.x; acc[1] += w*u0.y; acc[2]  += w*u0.z; acc[3]  += w*u0.w;
        acc[4] += w*u1.x; acc[5] += w*u1.y; acc[6]  += w*u1.z; acc[7]  += w*u1.w;
        acc[8] += w*u2.x; acc[9] += w*u2.y; acc[10] += w*u2.z; acc[11] += w*u2.w;
    }
    #pragma unroll
    for (int c = 0; c < PAD; ++c){
        float r = acc[c];
        #pragma unroll
        for (int off = 8; off >= 1; off >>= 1) r += __shfl_xor(r, off, 16);
        acc[c] = r;
    }
    // lane l16 handles channel l16
    float v = acc[0];
    #pragma unroll
    for (int c = 1; c < PAD; ++c) v = (l16 == c) ? acc[c] : v;
    if (l16 < CC){
        v += Db[row*PAD + l16];
        if (add_fw) v += FW[row*PAD + l16];
    } else {
        v = 0.f;
    }
    if (final_step){
        if (l16 < CC) uout[(size_t)row*CC + l16] = v;
    } else {
        v *= invs1[row];
        if (l16 < PAD) uout[(size_t)row*PAD + l16] = v;
    }
}

extern "C" void kernel_launch(void* const* d_in, const int* in_sizes, int n_in,
                              void* d_out, int out_size, void* d_ws, size_t ws_size,
                              hipStream_t stream){
    const float* h    = (const float*)d_in[0];
    const float* W    = (const float*)d_in[1];
    const float* a    = (const float*)d_in[2];
    const float* W1   = (const float*)d_in[3];
    const float* feat = (const float*)d_in[4];
    const int* ei     = (const int*)d_in[5];
    const int* idx_tr = (const int*)d_in[6];
    const int* labels = (const int*)d_in[7];
    float* out = (float*)d_out;

    char* wsp = (char*)d_ws;
    auto alloc = [&](size_t bytes)->void*{
        void* p = (void*)wsp;
        wsp += (bytes + 255) & ~(size_t)255;
        return p;
    };
    uint32_t* csrc2 = (uint32_t*)alloc((size_t)NN*CAP*4);   // 3 MB
    uint2*    tabc  = (uint2*)   alloc((size_t)NN*CAP*8);   // 6 MB
    float*    s1p   = (float*)   alloc((size_t)FB*NN*4);    // 4 MB
    uint32_t* cnt   = (uint32_t*)alloc(NN*4);
    float*    invs1 = (float*)   alloc(NN*4);
    float*    s_src = (float*)   alloc(NN*4);
    float*    s_dst = (float*)   alloc(NN*4);
    float*    FW    = (float*)   alloc((size_t)NN*PAD*4);
    float*    Db    = (float*)   alloc((size_t)NN*PAD*4);
    float*    uA    = (float*)   alloc((size_t)NN*PAD*4);
    float*    uB    = (float*)   alloc((size_t)NN*PAD*4);

    k_init <<<256, 1024, 0, stream>>>(W, a, h, feat, W1, idx_tr, labels,
                                      csrc2, s_src, s_dst, FW, Db);
    k_build<<<EE/256, 256, 0, stream>>>(ei, csrc2);
    k_fixup<<<FB, 1024, 0, stream>>>(csrc2, s_src, s_dst, tabc, cnt, s1p);
    k_s1red<<<NN/256, 256, 0, stream>>>(s1p, tabc, cnt, Db, invs1, uA);

    // uA holds u-hat-1; steps t=2..10: even t -> uB, odd t -> uA, t=10 -> out
    const float* cur = uA;
    for (int t = 2; t <= 10; ++t){
        float* dst = (t == 10) ? out : ((t & 1) ? uA : uB);
        k_spmv<<<NN/16, 256, 0, stream>>>(cnt, tabc, cur, Db, FW, invs1, dst,
                                          (t == 7) ? 1 : 0, (t == 10) ? 1 : 0);
        cur = dst;
    }
}